// Round 3
// baseline (87279.694 us; speedup 1.0000x reference)
//
#include <hip/hip_runtime.h>
#include <math.h>

#define HD 512
#define TT 512
#define NB 128
#define MAGIC 0x13579BDFu
typedef unsigned int uint;

__device__ __forceinline__ float sigm(float v) { return 1.0f / (1.0f + __expf(-v)); }

// x: [128][512] -> xT: [512][128]
__global__ __launch_bounds__(256) void transpose_x(const float* __restrict__ x,
                                                   float* __restrict__ xT) {
    __shared__ float tile[32][33];
    int bx = blockIdx.x * 32;   // t block
    int by = blockIdx.y * 32;   // b block
    int tx = threadIdx.x & 31, ty = threadIdx.x >> 5;  // 32 x 8
    #pragma unroll
    for (int i = 0; i < 32; i += 8)
        tile[ty + i][tx] = x[(by + ty + i) * TT + bx + tx];
    __syncthreads();
    #pragma unroll
    for (int i = 0; i < 32; i += 8)
        xT[(bx + ty + i) * NB + by + tx] = tile[tx][ty + i];
}

// Two-level monotonic barrier over the 128 unit-group WGs of one batch-group.
__device__ __forceinline__ void gbar(uint* mybar, int subid, uint n) {
    __threadfence();              // release my h writes
    __syncthreads();
    if (threadIdx.x == 0) {
        uint old = __hip_atomic_fetch_add(mybar + subid * 32, 1u,
                                          __ATOMIC_ACQ_REL, __HIP_MEMORY_SCOPE_AGENT);
        if (old == 32u * (n + 1u) - 1u) {
            uint r = __hip_atomic_fetch_add(mybar + 4 * 32, 1u,
                                            __ATOMIC_ACQ_REL, __HIP_MEMORY_SCOPE_AGENT);
            if (r == 4u * (n + 1u) - 1u)
                __hip_atomic_store(mybar + 5 * 32, n + 1u,
                                   __ATOMIC_RELEASE, __HIP_MEMORY_SCOPE_AGENT);
        }
        while (__hip_atomic_load(mybar + 5 * 32, __ATOMIC_RELAXED,
                                 __HIP_MEMORY_SCOPE_AGENT) < n + 1u)
            __builtin_amdgcn_s_sleep(2);
    }
    __syncthreads();
    __threadfence();              // acquire others' h writes
}

#define LOADC(BUF, C) { _Pragma("unroll") \
    for (int j = 0; j < 32; ++j) BUF[j] = hsrc[(kb + (C) * 32 + j) * 64 + lane]; }

#define FMAE(BUF, C) { _Pragma("unroll") \
    for (int j = 0; j < 32; ++j) { \
        const int kk = kb + (C) * 32 + j; const float hh = BUF[j]; \
        aR0 = fmaf(wR[kk],          hh, aR0); aZ0 = fmaf(wZ[kk],          hh, aZ0); aN0 = fmaf(wN[kk],          hh, aN0); \
        aR1 = fmaf(wR[HD + kk],     hh, aR1); aZ1 = fmaf(wZ[HD + kk],     hh, aZ1); aN1 = fmaf(wN[HD + kk],     hh, aN1); \
        aR2 = fmaf(wR[2 * HD + kk], hh, aR2); aZ2 = fmaf(wZ[2 * HD + kk], hh, aZ2); aN2 = fmaf(wN[2 * HD + kk], hh, aN2); \
        aR3 = fmaf(wR[3 * HD + kk], hh, aR3); aZ3 = fmaf(wZ[3 * HD + kk], hh, aZ3); aN3 = fmaf(wN[3 * HD + kk], hh, aN3); } }

#define FMAD(BUF, C) { _Pragma("unroll") \
    for (int j = 0; j < 32; ++j) { \
        const int kk = kb + (C) * 32 + j; const float hh = BUF[j]; \
        aR0 = fmaf(wR[kk],          hh, aR0); aZ0 = fmaf(wZ[kk],          hh, aZ0); aN0 = fmaf(wN[kk],          hh, aN0); \
        aR1 = fmaf(wR[HD + kk],     hh, aR1); aZ1 = fmaf(wZ[HD + kk],     hh, aZ1); aN1 = fmaf(wN[HD + kk],     hh, aN1); \
        aR2 = fmaf(wR[2 * HD + kk], hh, aR2); aZ2 = fmaf(wZ[2 * HD + kk], hh, aZ2); aN2 = fmaf(wN[2 * HD + kk], hh, aN2); \
        aR3 = fmaf(wR[3 * HD + kk], hh, aR3); aZ3 = fmaf(wZ[3 * HD + kk], hh, aZ3); aN3 = fmaf(wN[3 * HD + kk], hh, aN3); \
        ay  = fmaf(lw[kk],          hh, ay); } }

// 256 WGs = 2 batch-groups x 128 unit-groups; 256 threads = 4 waves.
// Wave w: partial dot over k in [128w, 128w+128) for units u0..u0+3; finalizes unit u0+w.
// h global layout: hbuf[phase][bg][k][64b] (contiguous 128 KB per WG slice).
__global__ __launch_bounds__(256, 1) void gru_ae(
    const float* __restrict__ xT,
    const float* __restrict__ eWi, const float* __restrict__ eWh,
    const float* __restrict__ ebi, const float* __restrict__ ebh,
    const float* __restrict__ dWi, const float* __restrict__ dWh,
    const float* __restrict__ dbi, const float* __restrict__ dbh,
    const float* __restrict__ linW, const float* __restrict__ linb,
    float* __restrict__ hbuf, uint* __restrict__ bar,
    float* __restrict__ out)
{
    const int bg   = blockIdx.x >> 7;
    const int wgu  = blockIdx.x & 127;
    const int lane = threadIdx.x & 63;
    const int wv   = __builtin_amdgcn_readfirstlane(threadIdx.x >> 6); // 0..3
    const int kb   = wv * 128;
    const int u    = wgu * 4 + wv;        // unit this wave finalizes
    const int col  = bg * 64 + lane;      // batch column
    const int subid = wgu >> 5;
    uint* mybar = bar + bg * 8 * 32;

    __shared__ float part[4][13][64];

    // init barrier counters
    if (wgu == 0 && threadIdx.x == 0) {
        for (int i = 0; i < 6; ++i)
            __hip_atomic_store(mybar + i * 32, 0u, __ATOMIC_RELAXED, __HIP_MEMORY_SCOPE_AGENT);
        __hip_atomic_store(mybar + 6 * 32, MAGIC, __ATOMIC_RELEASE, __HIP_MEMORY_SCOPE_AGENT);
    }
    if (threadIdx.x == 0) {
        while (__hip_atomic_load(mybar + 6 * 32, __ATOMIC_ACQUIRE,
                                 __HIP_MEMORY_SCOPE_AGENT) != MAGIC)
            __builtin_amdgcn_s_sleep(2);
    }
    __syncthreads();

    // zero h phase 0 (each wave writes its finalize-unit row)
    hbuf[(size_t)((0 * 2 + bg) * HD + u) * 64 + lane] = 0.0f;

    uint bn = 0;
    gbar(mybar, subid, bn); ++bn;

    const float lb = linb[0];
    const float* lw = linW;
    int p = 0;

    // ---------------- encoder ----------------
    {
        const float* wR = eWh + (size_t)(0 * HD + wgu * 4) * HD;
        const float* wZ = eWh + (size_t)(1 * HD + wgu * 4) * HD;
        const float* wN = eWh + (size_t)(2 * HD + wgu * 4) * HD;
        const float wi_r = eWi[u], wi_z = eWi[HD + u], wi_n = eWi[2 * HD + u];
        const float cr = ebi[u] + ebh[u];
        const float cz = ebi[HD + u] + ebh[HD + u];
        const float bin = ebi[2 * HD + u], bhn = ebh[2 * HD + u];

        for (int s = 0; s < TT; ++s) {
            const float* hsrc = hbuf + (size_t)((p * 2 + bg) * HD) * 64;
            float hprev = hsrc[u * 64 + lane];
            float aR0=0,aZ0=0,aN0=0,aR1=0,aZ1=0,aN1=0,aR2=0,aZ2=0,aN2=0,aR3=0,aZ3=0,aN3=0;
            float b0[32], b1[32];
            LOADC(b0, 0)
            LOADC(b1, 1) FMAE(b0, 0)
            LOADC(b0, 2) FMAE(b1, 1)
            LOADC(b1, 3) FMAE(b0, 2)
            FMAE(b1, 3)

            part[wv][0][lane] = aR0; part[wv][1][lane]  = aZ0; part[wv][2][lane]  = aN0;
            part[wv][3][lane] = aR1; part[wv][4][lane]  = aZ1; part[wv][5][lane]  = aN1;
            part[wv][6][lane] = aR2; part[wv][7][lane]  = aZ2; part[wv][8][lane]  = aN2;
            part[wv][9][lane] = aR3; part[wv][10][lane] = aZ3; part[wv][11][lane] = aN3;
            __syncthreads();

            float ar = part[0][wv*3+0][lane] + part[1][wv*3+0][lane] + part[2][wv*3+0][lane] + part[3][wv*3+0][lane];
            float az = part[0][wv*3+1][lane] + part[1][wv*3+1][lane] + part[2][wv*3+1][lane] + part[3][wv*3+1][lane];
            float an = part[0][wv*3+2][lane] + part[1][wv*3+2][lane] + part[2][wv*3+2][lane] + part[3][wv*3+2][lane];

            float xt = xT[s * NB + col];
            float r = sigm(fmaf(xt, wi_r, cr) + ar);
            float z = sigm(fmaf(xt, wi_z, cz) + az);
            float n = tanhf(fmaf(xt, wi_n, bin) + r * (an + bhn));
            float hv = fmaf(z, hprev - n, n);
            hbuf[(size_t)(((p ^ 1) * 2 + bg) * HD + u) * 64 + lane] = hv;
            p ^= 1;
            gbar(mybar, subid, bn); ++bn;
        }
    }

    // ---------------- decoder ----------------
    {
        const float* wR = dWh + (size_t)(0 * HD + wgu * 4) * HD;
        const float* wZ = dWh + (size_t)(1 * HD + wgu * 4) * HD;
        const float* wN = dWh + (size_t)(2 * HD + wgu * 4) * HD;
        const float wi_r = dWi[u], wi_z = dWi[HD + u], wi_n = dWi[2 * HD + u];
        const float cr = dbi[u] + dbh[u];
        const float cz = dbi[HD + u] + dbh[HD + u];
        const float bin = dbi[2 * HD + u], bhn = dbh[2 * HD + u];

        for (int s = 0; s < TT; ++s) {
            const float* hsrc = hbuf + (size_t)((p * 2 + bg) * HD) * 64;
            float hprev = hsrc[u * 64 + lane];
            float aR0=0,aZ0=0,aN0=0,aR1=0,aZ1=0,aN1=0,aR2=0,aZ2=0,aN2=0,aR3=0,aZ3=0,aN3=0;
            float ay = 0.0f;
            float b0[32], b1[32];
            LOADC(b0, 0)
            LOADC(b1, 1) FMAD(b0, 0)
            LOADC(b0, 2) FMAD(b1, 1)
            LOADC(b1, 3) FMAD(b0, 2)
            FMAD(b1, 3)

            part[wv][0][lane] = aR0; part[wv][1][lane]  = aZ0; part[wv][2][lane]  = aN0;
            part[wv][3][lane] = aR1; part[wv][4][lane]  = aZ1; part[wv][5][lane]  = aN1;
            part[wv][6][lane] = aR2; part[wv][7][lane]  = aZ2; part[wv][8][lane]  = aN2;
            part[wv][9][lane] = aR3; part[wv][10][lane] = aZ3; part[wv][11][lane] = aN3;
            part[wv][12][lane] = ay;
            __syncthreads();

            float ar = part[0][wv*3+0][lane] + part[1][wv*3+0][lane] + part[2][wv*3+0][lane] + part[3][wv*3+0][lane];
            float az = part[0][wv*3+1][lane] + part[1][wv*3+1][lane] + part[2][wv*3+1][lane] + part[3][wv*3+1][lane];
            float an = part[0][wv*3+2][lane] + part[1][wv*3+2][lane] + part[2][wv*3+2][lane] + part[3][wv*3+2][lane];
            float y  = part[0][12][lane] + part[1][12][lane] + part[2][12][lane] + part[3][12][lane] + lb;

            if (wgu == 0 && wv == 0 && s > 0)
                out[col * TT + (TT - s)] = y;

            float r = sigm(fmaf(y, wi_r, cr) + ar);
            float z = sigm(fmaf(y, wi_z, cz) + az);
            float n = tanhf(fmaf(y, wi_n, bin) + r * (an + bhn));
            float hv = fmaf(z, hprev - n, n);
            hbuf[(size_t)(((p ^ 1) * 2 + bg) * HD + u) * 64 + lane] = hv;
            p ^= 1;
            gbar(mybar, subid, bn); ++bn;
        }
    }

    // final y = lin(h_last) -> out[:, 0]
    {
        const float* hsrc = hbuf + (size_t)((p * 2 + bg) * HD) * 64;
        float ay = 0.0f;
        #pragma unroll 16
        for (int k = 0; k < 128; ++k)
            ay = fmaf(lw[kb + k], hsrc[(kb + k) * 64 + lane], ay);
        part[wv][0][lane] = ay;
        __syncthreads();
        if (wgu == 0 && wv == 0) {
            float y = part[0][0][lane] + part[1][0][lane] + part[2][0][lane] + part[3][0][lane] + lb;
            out[col * TT + 0] = y;
        }
    }
}

extern "C" void kernel_launch(void* const* d_in, const int* in_sizes, int n_in,
                              void* d_out, int out_size, void* d_ws, size_t ws_size,
                              hipStream_t stream) {
    const float* x    = (const float*)d_in[0];
    const float* eWi  = (const float*)d_in[1];
    const float* eWh  = (const float*)d_in[2];
    const float* ebi  = (const float*)d_in[3];
    const float* ebh  = (const float*)d_in[4];
    const float* dWi  = (const float*)d_in[5];
    const float* dWh  = (const float*)d_in[6];
    const float* dbi  = (const float*)d_in[7];
    const float* dbh  = (const float*)d_in[8];
    const float* linW = (const float*)d_in[9];
    const float* linb = (const float*)d_in[10];
    float* out = (float*)d_out;

    float* hbuf = (float*)d_ws;                                   // 2*2*512*64 = 512 KB
    float* xT   = hbuf + 2 * 2 * HD * 64;                         // 512*128    = 256 KB
    uint*  bar  = (uint*)(xT + HD * NB);                          // 2 KB

    transpose_x<<<dim3(16, 4), dim3(256), 0, stream>>>(x, xT);
    gru_ae<<<dim3(256), dim3(256), 0, stream>>>(xT, eWi, eWh, ebi, ebh,
                                                dWi, dWh, dbi, dbh,
                                                linW, linb, hbuf, bar, out);
}

// Round 4
// 25464.096 us; speedup vs baseline: 3.4276x; 3.4276x over previous
//
#include <hip/hip_runtime.h>
#include <math.h>

#define HD 512
#define TT 512
#define NB 128
#define MAGIC 0x13579BDFu
typedef unsigned int uint;

__device__ __forceinline__ float sigm(float v) { return 1.0f / (1.0f + __expf(-v)); }

// Cross-WG data: relaxed agent-scope atomics -> per-access L1/L2 bypass (sc0 sc1),
// coherent at LLC, NO buffer_inv / buffer_wbl2 cache maintenance.
__device__ __forceinline__ float2 gld2(const float2* p) {
    unsigned long long v = __hip_atomic_load((const unsigned long long*)p,
                                             __ATOMIC_RELAXED, __HIP_MEMORY_SCOPE_AGENT);
    union { unsigned long long u; float2 f; } c; c.u = v; return c.f;
}
__device__ __forceinline__ void gst(float* p, float v) {
    __hip_atomic_store(p, v, __ATOMIC_RELAXED, __HIP_MEMORY_SCOPE_AGENT);
}

// x: [128][512] -> xT: [512][128]
__global__ __launch_bounds__(256) void transpose_x(const float* __restrict__ x,
                                                   float* __restrict__ xT) {
    __shared__ float tile[32][33];
    int bx = blockIdx.x * 32;
    int by = blockIdx.y * 32;
    int tx = threadIdx.x & 31, ty = threadIdx.x >> 5;
    #pragma unroll
    for (int i = 0; i < 32; i += 8)
        tile[ty + i][tx] = x[(by + ty + i) * TT + bx + tx];
    __syncthreads();
    #pragma unroll
    for (int i = 0; i < 32; i += 8)
        xT[(bx + ty + i) * NB + by + tx] = tile[tx][ty + i];
}

// Two-level barrier over 128 WGs of one batch-group. NO fences: the
// __syncthreads entry drains vmcnt(0) (h stores are at the coherent point
// before the leader's arrive); all shared data is sc-bypassing, so no
// invalidate is needed on the wake side.
__device__ __forceinline__ void gbar(uint* mybar, int subid, uint n) {
    __syncthreads();
    if (threadIdx.x == 0) {
        uint old = __hip_atomic_fetch_add(mybar + subid * 32, 1u,
                                          __ATOMIC_RELAXED, __HIP_MEMORY_SCOPE_AGENT);
        if (old == 32u * (n + 1u) - 1u) {
            uint r = __hip_atomic_fetch_add(mybar + 4 * 32, 1u,
                                            __ATOMIC_RELAXED, __HIP_MEMORY_SCOPE_AGENT);
            if (r == 4u * (n + 1u) - 1u)
                __hip_atomic_store(mybar + 5 * 32, n + 1u,
                                   __ATOMIC_RELAXED, __HIP_MEMORY_SCOPE_AGENT);
        }
        while (__hip_atomic_load(mybar + 5 * 32, __ATOMIC_RELAXED,
                                 __HIP_MEMORY_SCOPE_AGENT) < n + 1u)
            __builtin_amdgcn_s_sleep(1);
    }
    __syncthreads();
}

// h stored as float2 pairs: h2[(phase*2+bg)*256 + k2][lane], k2 = k/2.
#define LOADC(BUF, C) { _Pragma("unroll") \
    for (int j = 0; j < 32; ++j) \
        BUF[j] = gld2(h2src + (size_t)(kb2 + (C) * 32 + j) * 64 + lane); }

#define FMAE(BUF, C) { _Pragma("unroll") \
    for (int j = 0; j < 32; ++j) { \
        const int k0 = (kb2 + (C) * 32 + j) * 2; \
        const float ha = BUF[j].x, hb = BUF[j].y; \
        aR0 = fmaf(wR[k0+1],      hb, fmaf(wR[k0],      ha, aR0)); \
        aZ0 = fmaf(wZ[k0+1],      hb, fmaf(wZ[k0],      ha, aZ0)); \
        aN0 = fmaf(wN[k0+1],      hb, fmaf(wN[k0],      ha, aN0)); \
        aR1 = fmaf(wR[HD+k0+1],   hb, fmaf(wR[HD+k0],   ha, aR1)); \
        aZ1 = fmaf(wZ[HD+k0+1],   hb, fmaf(wZ[HD+k0],   ha, aZ1)); \
        aN1 = fmaf(wN[HD+k0+1],   hb, fmaf(wN[HD+k0],   ha, aN1)); \
        aR2 = fmaf(wR[2*HD+k0+1], hb, fmaf(wR[2*HD+k0], ha, aR2)); \
        aZ2 = fmaf(wZ[2*HD+k0+1], hb, fmaf(wZ[2*HD+k0], ha, aZ2)); \
        aN2 = fmaf(wN[2*HD+k0+1], hb, fmaf(wN[2*HD+k0], ha, aN2)); \
        aR3 = fmaf(wR[3*HD+k0+1], hb, fmaf(wR[3*HD+k0], ha, aR3)); \
        aZ3 = fmaf(wZ[3*HD+k0+1], hb, fmaf(wZ[3*HD+k0], ha, aZ3)); \
        aN3 = fmaf(wN[3*HD+k0+1], hb, fmaf(wN[3*HD+k0], ha, aN3)); } }

#define FMAD(BUF, C) { _Pragma("unroll") \
    for (int j = 0; j < 32; ++j) { \
        const int k0 = (kb2 + (C) * 32 + j) * 2; \
        const float ha = BUF[j].x, hb = BUF[j].y; \
        aR0 = fmaf(wR[k0+1],      hb, fmaf(wR[k0],      ha, aR0)); \
        aZ0 = fmaf(wZ[k0+1],      hb, fmaf(wZ[k0],      ha, aZ0)); \
        aN0 = fmaf(wN[k0+1],      hb, fmaf(wN[k0],      ha, aN0)); \
        aR1 = fmaf(wR[HD+k0+1],   hb, fmaf(wR[HD+k0],   ha, aR1)); \
        aZ1 = fmaf(wZ[HD+k0+1],   hb, fmaf(wZ[HD+k0],   ha, aZ1)); \
        aN1 = fmaf(wN[HD+k0+1],   hb, fmaf(wN[HD+k0],   ha, aN1)); \
        aR2 = fmaf(wR[2*HD+k0+1], hb, fmaf(wR[2*HD+k0], ha, aR2)); \
        aZ2 = fmaf(wZ[2*HD+k0+1], hb, fmaf(wZ[2*HD+k0], ha, aZ2)); \
        aN2 = fmaf(wN[2*HD+k0+1], hb, fmaf(wN[2*HD+k0], ha, aN2)); \
        aR3 = fmaf(wR[3*HD+k0+1], hb, fmaf(wR[3*HD+k0], ha, aR3)); \
        aZ3 = fmaf(wZ[3*HD+k0+1], hb, fmaf(wZ[3*HD+k0], ha, aZ3)); \
        aN3 = fmaf(wN[3*HD+k0+1], hb, fmaf(wN[3*HD+k0], ha, aN3)); \
        ay  = fmaf(lw[k0+1],      hb, fmaf(lw[k0],      ha, ay)); } }

// 256 WGs = 2 batch-groups x 128 unit-groups; 256 threads = 4 waves.
// Wave wv: k in [128*wv, 128*wv+128) for units u0..u0+3; finalizes unit u0+wv.
__global__ __launch_bounds__(256, 1) void gru_ae(
    const float* __restrict__ xT,
    const float* __restrict__ eWi, const float* __restrict__ eWh,
    const float* __restrict__ ebi, const float* __restrict__ ebh,
    const float* __restrict__ dWi, const float* __restrict__ dWh,
    const float* __restrict__ dbi, const float* __restrict__ dbh,
    const float* __restrict__ linW, const float* __restrict__ linb,
    float* __restrict__ hbuf, uint* __restrict__ bar,
    float* __restrict__ out)
{
    const int bg    = blockIdx.x >> 7;
    const int wgu   = blockIdx.x & 127;
    const int lane  = threadIdx.x & 63;
    const int wv    = __builtin_amdgcn_readfirstlane(threadIdx.x >> 6); // 0..3
    const int kb2   = wv * 64;            // float2-pair base of this wave's k-range
    const int u0    = wgu * 4;
    const int u     = u0 + wv;            // unit this wave finalizes
    const int col   = bg * 64 + lane;     // batch column
    const int subid = wgu >> 5;
    uint* mybar = bar + bg * 8 * 32;

    __shared__ float part[4][13][64];

    // ---- init barrier counters (d_ws is poisoned each call) ----
    if (wgu == 0 && threadIdx.x == 0) {
        for (int i = 0; i < 6; ++i)
            __hip_atomic_store(mybar + i * 32, 0u, __ATOMIC_RELAXED, __HIP_MEMORY_SCOPE_AGENT);
        __builtin_amdgcn_s_waitcnt(0x0F70);   // vmcnt(0): zeros visible before MAGIC
        __hip_atomic_store(mybar + 6 * 32, MAGIC, __ATOMIC_RELAXED, __HIP_MEMORY_SCOPE_AGENT);
    }
    if (threadIdx.x == 0) {
        while (__hip_atomic_load(mybar + 6 * 32, __ATOMIC_RELAXED,
                                 __HIP_MEMORY_SCOPE_AGENT) != MAGIC)
            __builtin_amdgcn_s_sleep(1);
    }
    __syncthreads();

    // zero h phase 0: this wave's unit row (paired layout: element (u>>1, lane, u&1))
    gst(&hbuf[(size_t)((0 * 2 + bg) * 256 + (u >> 1)) * 128 + lane * 2 + (u & 1)], 0.0f);

    uint bn = 0;
    gbar(mybar, subid, bn); ++bn;

    const float lb = linb[0];
    const float* lw = linW;
    float hprev = 0.0f;   // own unit's h, register-resident
    int p = 0;

    // ---------------- encoder ----------------
    {
        const float* wR = eWh + (size_t)(0 * HD + u0) * HD;
        const float* wZ = eWh + (size_t)(1 * HD + u0) * HD;
        const float* wN = eWh + (size_t)(2 * HD + u0) * HD;
        const float wi_r = eWi[u], wi_z = eWi[HD + u], wi_n = eWi[2 * HD + u];
        const float cr  = ebi[u] + ebh[u];
        const float cz  = ebi[HD + u] + ebh[HD + u];
        const float bin = ebi[2 * HD + u], bhn = ebh[2 * HD + u];

        for (int s = 0; s < TT; ++s) {
            const float2* h2src = (const float2*)hbuf + (size_t)(p * 2 + bg) * 256 * 64;
            float xt = xT[s * NB + col];
            float aR0=0,aZ0=0,aN0=0,aR1=0,aZ1=0,aN1=0,aR2=0,aZ2=0,aN2=0,aR3=0,aZ3=0,aN3=0;
            float2 b0[32], b1[32];
            LOADC(b0, 0)
            LOADC(b1, 1)
            FMAE(b0, 0)
            FMAE(b1, 1)

            part[wv][0][lane] = aR0; part[wv][1][lane]  = aZ0; part[wv][2][lane]  = aN0;
            part[wv][3][lane] = aR1; part[wv][4][lane]  = aZ1; part[wv][5][lane]  = aN1;
            part[wv][6][lane] = aR2; part[wv][7][lane]  = aZ2; part[wv][8][lane]  = aN2;
            part[wv][9][lane] = aR3; part[wv][10][lane] = aZ3; part[wv][11][lane] = aN3;
            __syncthreads();

            float ar = part[0][wv*3+0][lane] + part[1][wv*3+0][lane] + part[2][wv*3+0][lane] + part[3][wv*3+0][lane];
            float az = part[0][wv*3+1][lane] + part[1][wv*3+1][lane] + part[2][wv*3+1][lane] + part[3][wv*3+1][lane];
            float an = part[0][wv*3+2][lane] + part[1][wv*3+2][lane] + part[2][wv*3+2][lane] + part[3][wv*3+2][lane];

            float r = sigm(fmaf(xt, wi_r, cr) + ar);
            float z = sigm(fmaf(xt, wi_z, cz) + az);
            float n = tanhf(fmaf(xt, wi_n, bin) + r * (an + bhn));
            float hv = fmaf(z, hprev - n, n);
            gst(&hbuf[(size_t)(((p ^ 1) * 2 + bg) * 256 + (u >> 1)) * 128 + lane * 2 + (u & 1)], hv);
            hprev = hv;
            p ^= 1;
            gbar(mybar, subid, bn); ++bn;
        }
    }

    // ---------------- decoder ----------------
    {
        const float* wR = dWh + (size_t)(0 * HD + u0) * HD;
        const float* wZ = dWh + (size_t)(1 * HD + u0) * HD;
        const float* wN = dWh + (size_t)(2 * HD + u0) * HD;
        const float wi_r = dWi[u], wi_z = dWi[HD + u], wi_n = dWi[2 * HD + u];
        const float cr  = dbi[u] + dbh[u];
        const float cz  = dbi[HD + u] + dbh[HD + u];
        const float bin = dbi[2 * HD + u], bhn = dbh[2 * HD + u];

        for (int s = 0; s < TT; ++s) {
            const float2* h2src = (const float2*)hbuf + (size_t)(p * 2 + bg) * 256 * 64;
            float aR0=0,aZ0=0,aN0=0,aR1=0,aZ1=0,aN1=0,aR2=0,aZ2=0,aN2=0,aR3=0,aZ3=0,aN3=0;
            float ay = 0.0f;
            float2 b0[32], b1[32];
            LOADC(b0, 0)
            LOADC(b1, 1)
            FMAD(b0, 0)
            FMAD(b1, 1)

            part[wv][0][lane] = aR0; part[wv][1][lane]  = aZ0; part[wv][2][lane]  = aN0;
            part[wv][3][lane] = aR1; part[wv][4][lane]  = aZ1; part[wv][5][lane]  = aN1;
            part[wv][6][lane] = aR2; part[wv][7][lane]  = aZ2; part[wv][8][lane]  = aN2;
            part[wv][9][lane] = aR3; part[wv][10][lane] = aZ3; part[wv][11][lane] = aN3;
            part[wv][12][lane] = ay;
            __syncthreads();

            float ar = part[0][wv*3+0][lane] + part[1][wv*3+0][lane] + part[2][wv*3+0][lane] + part[3][wv*3+0][lane];
            float az = part[0][wv*3+1][lane] + part[1][wv*3+1][lane] + part[2][wv*3+1][lane] + part[3][wv*3+1][lane];
            float an = part[0][wv*3+2][lane] + part[1][wv*3+2][lane] + part[2][wv*3+2][lane] + part[3][wv*3+2][lane];
            float y  = part[0][12][lane] + part[1][12][lane] + part[2][12][lane] + part[3][12][lane] + lb;

            if (wgu == 0 && wv == 0 && s > 0)
                out[col * TT + (TT - s)] = y;   // y_{s-1} -> column TT-1-(s-1)

            float r = sigm(fmaf(y, wi_r, cr) + ar);
            float z = sigm(fmaf(y, wi_z, cz) + az);
            float n = tanhf(fmaf(y, wi_n, bin) + r * (an + bhn));
            float hv = fmaf(z, hprev - n, n);
            gst(&hbuf[(size_t)(((p ^ 1) * 2 + bg) * 256 + (u >> 1)) * 128 + lane * 2 + (u & 1)], hv);
            hprev = hv;
            p ^= 1;
            gbar(mybar, subid, bn); ++bn;
        }
    }

    // final y_511 = lin(h_511) -> out[:, 0]
    if (wgu == 0) {
        const float2* h2src = (const float2*)hbuf + (size_t)(p * 2 + bg) * 256 * 64;
        float ay = 0.0f;
        #pragma unroll 16
        for (int j = 0; j < 64; ++j) {
            float2 hh = gld2(h2src + (size_t)(kb2 + j) * 64 + lane);
            const int k0 = (kb2 + j) * 2;
            ay = fmaf(lw[k0 + 1], hh.y, fmaf(lw[k0], hh.x, ay));
        }
        part[wv][0][lane] = ay;
        __syncthreads();
        if (wv == 0) {
            float y = part[0][0][lane] + part[1][0][lane] + part[2][0][lane] + part[3][0][lane] + lb;
            out[col * TT + 0] = y;
        }
    }
}

extern "C" void kernel_launch(void* const* d_in, const int* in_sizes, int n_in,
                              void* d_out, int out_size, void* d_ws, size_t ws_size,
                              hipStream_t stream) {
    const float* x    = (const float*)d_in[0];
    const float* eWi  = (const float*)d_in[1];
    const float* eWh  = (const float*)d_in[2];
    const float* ebi  = (const float*)d_in[3];
    const float* ebh  = (const float*)d_in[4];
    const float* dWi  = (const float*)d_in[5];
    const float* dWh  = (const float*)d_in[6];
    const float* dbi  = (const float*)d_in[7];
    const float* dbh  = (const float*)d_in[8];
    const float* linW = (const float*)d_in[9];
    const float* linb = (const float*)d_in[10];
    float* out = (float*)d_out;

    float* hbuf = (float*)d_ws;                                   // 2*2*512*64 floats = 512 KB
    float* xT   = hbuf + 2 * 2 * HD * 64;                         // 256 KB
    uint*  bar  = (uint*)(xT + HD * NB);                          // 2 KB

    transpose_x<<<dim3(16, 4), dim3(256), 0, stream>>>(x, xT);
    gru_ae<<<dim3(256), dim3(256), 0, stream>>>(xT, eWi, eWh, ebi, ebh,
                                                dWi, dWh, dbi, dbh,
                                                linW, linb, hbuf, bar, out);
}